// Round 3
// baseline (224.979 us; speedup 1.0000x reference)
//
#include <hip/hip_runtime.h>
#include <hip/hip_cooperative_groups.h>

namespace cg = cooperative_groups;

// LinearAttention: B=1, H=16, N=2048, D=DV=64, causal=1, f32 in/out.
// Single cooperative kernel: phase1 (chunk sums) -> grid.sync ->
// phase2 (exclusive chunk prefix) -> grid.sync -> phase3 (output).
// Q/K/V staged to LDS ONCE (persist across grid.sync); Kf^T buffer reused as W.
#define Hh   16
#define Nn   2048
#define Dd   64
#define DVv  64
#define Ll   64
#define Cc   (Nn / Ll)      // 32
#define HCc  (Hh * Cc)      // 512
#define EPSf 1e-6f
#define LDP  72             // bf16 row stride (+8 pad, keeps 16B align)

typedef __attribute__((ext_vector_type(8))) __bf16 bf16x8;
typedef __attribute__((ext_vector_type(4))) __bf16 bf16x4;
typedef __attribute__((ext_vector_type(4))) float  f32x4;

__device__ __forceinline__ float fmap(float x) {
    return x > 0.0f ? (x + 1.0f) : __expf(x);   // elu(x)+1
}
__device__ __forceinline__ __bf16 tobf(float x) { return (__bf16)x; }

__global__ __launch_bounds__(256) void k_fused(
    const float* __restrict__ Qg, const float* __restrict__ Kg,
    const float* __restrict__ Vg, float* __restrict__ Sws,
    float* __restrict__ zws, float* __restrict__ Og)
{
    __shared__ __align__(16) __bf16 aQ[Ll][LDP];    // Qf row-major (A operand)
    __shared__ __align__(16) __bf16 aK[Ll][LDP];    // Kf row-major (B^T for W-GEMM)
    __shared__ __align__(16) __bf16 sT[Ll][LDP];    // Kf^T (phase1 A), reused as masked W (phase3 A)
    __shared__ __align__(16) __bf16 bV[80][LDP];    // V^T; row 64 = ones; 65..79 = 0
    __shared__ __align__(16) __bf16 bS[80][LDP];    // Spre^T; row 64 = z_pre; 65..79 = 0

    const int t  = threadIdx.x;
    const int hc = blockIdx.x;
    const int lane = t & 63, wv = t >> 6;
    const int col = lane & 15, quad = lane >> 4;
    cg::grid_group grid = cg::this_grid();

    // ---------------- Phase 1 staging: Qf, Kf, Kf^T, V^T ----------------
    {
        const float4* Q4 = (const float4*)(Qg + (size_t)hc * (Ll * Dd));
        const float4* K4 = (const float4*)(Kg + (size_t)hc * (Ll * Dd));
        const float4* V4 = (const float4*)(Vg + (size_t)hc * (Ll * DVv));
        for (int i = t; i < (Ll * Dd) / 4; i += 256) {   // 4 iters
            float4 q4 = Q4[i];
            float4 k4 = K4[i];
            float4 v4 = V4[i];
            const int m  = i >> 4;
            const int c0 = (i & 15) * 4;
            float kf0 = fmap(k4.x), kf1 = fmap(k4.y), kf2 = fmap(k4.z), kf3 = fmap(k4.w);
            bf16x4 qv = { tobf(fmap(q4.x)), tobf(fmap(q4.y)), tobf(fmap(q4.z)), tobf(fmap(q4.w)) };
            bf16x4 kv = { tobf(kf0), tobf(kf1), tobf(kf2), tobf(kf3) };
            *(bf16x4*)&aQ[m][c0] = qv;
            *(bf16x4*)&aK[m][c0] = kv;
            sT[c0 + 0][m] = kv[0];
            sT[c0 + 1][m] = kv[1];
            sT[c0 + 2][m] = kv[2];
            sT[c0 + 3][m] = kv[3];
            bV[c0 + 0][m] = tobf(v4.x);
            bV[c0 + 1][m] = tobf(v4.y);
            bV[c0 + 2][m] = tobf(v4.z);
            bV[c0 + 3][m] = tobf(v4.w);
        }
        for (int i = t; i < 16 * LDP; i += 256) {        // aux rows 64..79
            const int r = i / LDP, c = i % LDP;
            bV[64 + r][c] = (r == 0) ? (__bf16)1.0f : (__bf16)0.0f;
        }
    }
    __syncthreads();

    // ---------------- Phase 1 compute: S_c = Kf^T V, z_c = Kf^T . ones --------
    {
        float* So = Sws + (size_t)hc * (Dd * DVv);
        for (int et = 0; et < 5; ++et) {
            f32x4 acc = {0.f, 0.f, 0.f, 0.f};
#pragma unroll
            for (int ks = 0; ks < 2; ++ks) {
                bf16x8 a = *(const bf16x8*)&sT[wv * 16 + col][ks * 32 + quad * 8];
                bf16x8 b = *(const bf16x8*)&bV[et * 16 + col][ks * 32 + quad * 8];
                acc = __builtin_amdgcn_mfma_f32_16x16x32_bf16(a, b, acc, 0, 0, 0);
            }
            if (et < 4) {
#pragma unroll
                for (int j = 0; j < 4; ++j) {
                    const int d = wv * 16 + quad * 4 + j;
                    So[d * DVv + et * 16 + col] = acc[j];
                }
            } else if (col == 0) {
#pragma unroll
                for (int j = 0; j < 4; ++j) {
                    const int d = wv * 16 + quad * 4 + j;
                    zws[hc * Dd + d] = acc[j];
                }
            }
        }
    }
    grid.sync();

    // ---------------- Phase 2: exclusive prefix over chunk axis ----------------
    {
        const int gid = blockIdx.x * 256 + t;            // [0, 131072)
        if (gid < Hh * Dd * DVv) {                       // 65536 scans of length 32
            const int h  = gid >> 12;
            const int el = gid & 4095;
            float* base = Sws + ((size_t)h * Cc) * (Dd * DVv) + el;
            float v[Cc];
#pragma unroll
            for (int c = 0; c < Cc; ++c) v[c] = base[c * (Dd * DVv)];
            float run = 0.0f;
#pragma unroll
            for (int c = 0; c < Cc; ++c) { base[c * (Dd * DVv)] = run; run += v[c]; }
        }
        if (gid < Hh * Dd) {                             // 1024 z-scans
            const int zh = gid >> 6, zd = gid & 63;
            float* zb = zws + zh * Cc * Dd + zd;
            float zv[Cc];
#pragma unroll
            for (int c = 0; c < Cc; ++c) zv[c] = zb[c * Dd];
            float zr = 0.0f;
#pragma unroll
            for (int c = 0; c < Cc; ++c) { zb[c * Dd] = zr; zr += zv[c]; }
        }
    }
    grid.sync();

    // ---------------- Phase 3 staging: Spre^T + z_pre row ----------------
    {
        const float4* S4 = (const float4*)(Sws + (size_t)hc * (Dd * DVv));
        const float*  zp = zws + hc * Dd;
        for (int i = t; i < (Dd * DVv) / 4; i += 256) {
            float4 s4 = S4[i];
            const int d  = i >> 4;
            const int e0 = (i & 15) * 4;
            bS[e0 + 0][d] = tobf(s4.x);
            bS[e0 + 1][d] = tobf(s4.y);
            bS[e0 + 2][d] = tobf(s4.z);
            bS[e0 + 3][d] = tobf(s4.w);
        }
        for (int i = t; i < 16 * LDP; i += 256) {
            const int r = i / LDP, c = i % LDP;
            bS[64 + r][c] = (r == 0 && c < Dd) ? tobf(zp[c]) : (__bf16)0.0f;
        }
    }

    // W-GEMM: W = Qf Kf^T, causal-masked, written into sT (Kf^T dead after phase 1)
#pragma unroll 1
    for (int mt = 0; mt < 4; ++mt) {
        f32x4 wacc = {0.f, 0.f, 0.f, 0.f};
#pragma unroll
        for (int ks = 0; ks < 2; ++ks) {
            bf16x8 a = *(const bf16x8*)&aQ[wv * 16 + col][ks * 32 + quad * 8];
            bf16x8 b = *(const bf16x8*)&aK[mt * 16 + col][ks * 32 + quad * 8];
            wacc = __builtin_amdgcn_mfma_f32_16x16x32_bf16(a, b, wacc, 0, 0, 0);
        }
#pragma unroll
        for (int j = 0; j < 4; ++j) {
            const int n = wv * 16 + quad * 4 + j;
            const int m = mt * 16 + col;
            sT[n][m] = tobf(m <= n ? wacc[j] : 0.0f);
        }
    }
    __syncthreads();

    // O-GEMM: acc[et] = Wm.(V^T row-block) + Qf.(Spre^T row-block); et=4 -> den
    f32x4 accs[5];
#pragma unroll 1
    for (int et = 0; et < 5; ++et) {
        f32x4 acc = {0.f, 0.f, 0.f, 0.f};
#pragma unroll
        for (int ks = 0; ks < 2; ++ks) {
            bf16x8 a = *(const bf16x8*)&sT[wv * 16 + col][ks * 32 + quad * 8];
            bf16x8 b = *(const bf16x8*)&bV[et * 16 + col][ks * 32 + quad * 8];
            acc = __builtin_amdgcn_mfma_f32_16x16x32_bf16(a, b, acc, 0, 0, 0);
        }
#pragma unroll
        for (int ks = 0; ks < 2; ++ks) {
            bf16x8 a = *(const bf16x8*)&aQ[wv * 16 + col][ks * 32 + quad * 8];
            bf16x8 b = *(const bf16x8*)&bS[et * 16 + col][ks * 32 + quad * 8];
            acc = __builtin_amdgcn_mfma_f32_16x16x32_bf16(a, b, acc, 0, 0, 0);
        }
        accs[et] = acc;
    }
    float dn[4];
#pragma unroll
    for (int j = 0; j < 4; ++j) dn[j] = __shfl(accs[4][j], lane & 48);

    float* Oc = Og + (size_t)hc * (Ll * DVv);
#pragma unroll
    for (int et = 0; et < 4; ++et) {
#pragma unroll
        for (int j = 0; j < 4; ++j) {
            const int n = wv * 16 + quad * 4 + j;
            Oc[n * DVv + et * 16 + col] = accs[et][j] / (dn[j] + EPSf);
        }
    }
}

extern "C" void kernel_launch(void* const* d_in, const int* in_sizes, int n_in,
                              void* d_out, int out_size, void* d_ws, size_t ws_size,
                              hipStream_t stream) {
    const float* Q = (const float*)d_in[0];
    const float* K = (const float*)d_in[1];
    const float* V = (const float*)d_in[2];
    float* Sws = (float*)d_ws;                          // HC * 64*64 f32 = 8 MB
    float* zws = Sws + (size_t)HCc * Dd * DVv;          // HC * 64 f32
    float* out = (float*)d_out;

    void* args[] = { (void*)&Q, (void*)&K, (void*)&V,
                     (void*)&Sws, (void*)&zws, (void*)&out };
    hipLaunchCooperativeKernel((const void*)k_fused, dim3(HCc), dim3(256),
                               args, 0, stream);
}

// Round 4
// 95.067 us; speedup vs baseline: 2.3665x; 2.3665x over previous
//
#include <hip/hip_runtime.h>

// LinearAttention: B=1, H=16, N=2048, D=DV=64, causal=1, f32 in/out.
// Two dispatches:
//  k1: per-chunk S_c^T = (Kf^T V)^T stored bf16, z_c = colsum(Kf) f32.
//  k2: per-chunk on-the-fly prefix reduction of S^T/z (L2/L3-resident),
//      then W = mask(Qf Kf^T), O = W V + Qf S_pre, den fused as extra column.
#define Hh   16
#define Nn   2048
#define Dd   64
#define DVv  64
#define Ll   64
#define Cc   (Nn / Ll)      // 32
#define HCc  (Hh * Cc)      // 512
#define EPSf 1e-6f
#define LDP  72             // bf16 row stride (+8 pad, keeps 16B align)

typedef __attribute__((ext_vector_type(8))) __bf16 bf16x8;
typedef __attribute__((ext_vector_type(4))) __bf16 bf16x4;
typedef __attribute__((ext_vector_type(4))) float  f32x4;

__device__ __forceinline__ float fmap(float x) {
    return x > 0.0f ? (x + 1.0f) : __expf(x);   // elu(x)+1
}
__device__ __forceinline__ __bf16 tobf(float x) { return (__bf16)x; }

// ---------------- k1: S_c^T (bf16) + z_c (f32) ----------------
__global__ __launch_bounds__(256) void k_chunk_sums(
    const float* __restrict__ Kg, const float* __restrict__ Vg,
    __bf16* __restrict__ SwsT, float* __restrict__ zws)
{
    __shared__ __align__(16) __bf16 sKT[Dd][LDP];   // Kf^T: [d][m]
    __shared__ __align__(16) __bf16 sVT[80][LDP];   // V^T: [e][m]; row 64 = ones
    const int t  = threadIdx.x;
    const int hc = blockIdx.x;
    const float4* K4 = (const float4*)(Kg + (size_t)hc * (Ll * Dd));
    const float4* V4 = (const float4*)(Vg + (size_t)hc * (Ll * DVv));
    for (int i = t; i < (Ll * Dd) / 4; i += 256) {   // 4 iters
        float4 k4 = K4[i];
        float4 v4 = V4[i];
        const int m  = i >> 4;
        const int c0 = (i & 15) * 4;
        sKT[c0 + 0][m] = tobf(fmap(k4.x));
        sKT[c0 + 1][m] = tobf(fmap(k4.y));
        sKT[c0 + 2][m] = tobf(fmap(k4.z));
        sKT[c0 + 3][m] = tobf(fmap(k4.w));
        sVT[c0 + 0][m] = tobf(v4.x);
        sVT[c0 + 1][m] = tobf(v4.y);
        sVT[c0 + 2][m] = tobf(v4.z);
        sVT[c0 + 3][m] = tobf(v4.w);
    }
    for (int i = t; i < 16 * LDP; i += 256) {        // aux rows 64..79
        const int r = i / LDP, c = i % LDP;
        sVT[64 + r][c] = (r == 0) ? (__bf16)1.0f : (__bf16)0.0f;
    }
    __syncthreads();

    const int lane = t & 63, wv = t >> 6;
    const int col = lane & 15, quad = lane >> 4;
    __bf16* So = SwsT + (size_t)hc * (Dd * DVv);     // S^T layout: [e][d]
    for (int et = 0; et < 5; ++et) {
        f32x4 acc = {0.f, 0.f, 0.f, 0.f};
#pragma unroll
        for (int ks = 0; ks < 2; ++ks) {
            bf16x8 a = *(const bf16x8*)&sKT[wv * 16 + col][ks * 32 + quad * 8];
            bf16x8 b = *(const bf16x8*)&sVT[et * 16 + col][ks * 32 + quad * 8];
            acc = __builtin_amdgcn_mfma_f32_16x16x32_bf16(a, b, acc, 0, 0, 0);
        }
        if (et < 4) {
            // acc[j]: d = wv*16 + quad*4 + j (contig in j), e = et*16 + col
            const int e = et * 16 + col;
            const int d = wv * 16 + quad * 4;
            bf16x4 s4 = { tobf(acc[0]), tobf(acc[1]), tobf(acc[2]), tobf(acc[3]) };
            *(bf16x4*)&So[e * Dd + d] = s4;
        } else if (col == 0) {
#pragma unroll
            for (int j = 0; j < 4; ++j)
                zws[hc * Dd + wv * 16 + quad * 4 + j] = acc[j];
        }
    }
}

// ---------------- k2: prefix-reduce + W-GEMM + O-GEMM ----------------
__global__ __launch_bounds__(256) void k_output(
    const float* __restrict__ Qg, const float* __restrict__ Kg,
    const float* __restrict__ Vg, const __bf16* __restrict__ SwsT,
    const float* __restrict__ zws, float* __restrict__ Og)
{
    __shared__ __align__(16) __bf16 aQ[Ll][LDP];    // Qf rows (A)
    __shared__ __align__(16) __bf16 aK[Ll][LDP];    // Kf rows (B^T for W-GEMM)
    __shared__ __align__(16) __bf16 sW[Ll][LDP];    // masked W (A for O-GEMM)
    __shared__ __align__(16) __bf16 bV[80][LDP];    // V^T; row 64 = ones
    __shared__ __align__(16) __bf16 bS[80][LDP];    // Spre^T; row 64 = z_pre
    const int t  = threadIdx.x;
    const int hc = blockIdx.x;
    const int h  = hc >> 5, c = hc & 31;
    const int lane = t & 63, wv = t >> 6;
    const int col = lane & 15, quad = lane >> 4;

    // Stage Qf / Kf / V^T
    {
        const float4* Q4 = (const float4*)(Qg + (size_t)hc * (Ll * Dd));
        const float4* K4 = (const float4*)(Kg + (size_t)hc * (Ll * Dd));
        const float4* V4 = (const float4*)(Vg + (size_t)hc * (Ll * DVv));
        for (int i = t; i < (Ll * Dd) / 4; i += 256) {
            float4 q4 = Q4[i];
            float4 k4 = K4[i];
            float4 v4 = V4[i];
            const int m  = i >> 4;
            const int c0 = (i & 15) * 4;
            bf16x4 qv = { tobf(fmap(q4.x)), tobf(fmap(q4.y)), tobf(fmap(q4.z)), tobf(fmap(q4.w)) };
            bf16x4 kv = { tobf(fmap(k4.x)), tobf(fmap(k4.y)), tobf(fmap(k4.z)), tobf(fmap(k4.w)) };
            *(bf16x4*)&aQ[m][c0] = qv;
            *(bf16x4*)&aK[m][c0] = kv;
            bV[c0 + 0][m] = tobf(v4.x);
            bV[c0 + 1][m] = tobf(v4.y);
            bV[c0 + 2][m] = tobf(v4.z);
            bV[c0 + 3][m] = tobf(v4.w);
        }
        for (int i = t; i < 16 * LDP; i += 256) {
            const int r = i / LDP, cc = i % LDP;
            bV[64 + r][cc] = (r == 0) ? (__bf16)1.0f : (__bf16)0.0f;
        }
    }

    // On-the-fly exclusive prefix: sum S^T of chunks < c (L2/L3-resident reads)
    {
        const __bf16* Sb = SwsT + ((size_t)(h * Cc)) * (Dd * DVv) + t * 16;
        float racc[16];
#pragma unroll
        for (int j = 0; j < 16; ++j) racc[j] = 0.0f;
        for (int cc = 0; cc < c; ++cc) {
            bf16x8 s0 = *(const bf16x8*)(Sb + (size_t)cc * (Dd * DVv));
            bf16x8 s1 = *(const bf16x8*)(Sb + (size_t)cc * (Dd * DVv) + 8);
#pragma unroll
            for (int j = 0; j < 8; ++j) { racc[j] += (float)s0[j]; racc[8 + j] += (float)s1[j]; }
        }
        // element idx = t*16 + j = e*64 + d  ->  e = t>>2, d0 = (t&3)*16
        const int e = t >> 2, d0 = (t & 3) * 16;
#pragma unroll
        for (int j = 0; j < 16; ++j) bS[e][d0 + j] = tobf(racc[j]);

        if (t < Dd) {                                   // z prefix
            const float* zb = zws + (h * Cc) * Dd + t;
            float zr = 0.0f;
            for (int cc = 0; cc < c; ++cc) zr += zb[cc * Dd];
            bS[64][t] = tobf(zr);
        }
        for (int i = t; i < 16 * LDP; i += 256) {       // zero aux rows (skip z slots)
            const int r = i / LDP, cc = i % LDP;
            if (!(r == 0 && cc < Dd)) bS[64 + r][cc] = (__bf16)0.0f;
        }
    }
    __syncthreads();

    // W-GEMM: W = mask(Qf Kf^T)
#pragma unroll 1
    for (int mt = 0; mt < 4; ++mt) {
        f32x4 wacc = {0.f, 0.f, 0.f, 0.f};
#pragma unroll
        for (int ks = 0; ks < 2; ++ks) {
            bf16x8 a = *(const bf16x8*)&aQ[wv * 16 + col][ks * 32 + quad * 8];
            bf16x8 b = *(const bf16x8*)&aK[mt * 16 + col][ks * 32 + quad * 8];
            wacc = __builtin_amdgcn_mfma_f32_16x16x32_bf16(a, b, wacc, 0, 0, 0);
        }
#pragma unroll
        for (int j = 0; j < 4; ++j) {
            const int n = wv * 16 + quad * 4 + j;
            const int m = mt * 16 + col;
            sW[n][m] = tobf(m <= n ? wacc[j] : 0.0f);
        }
    }
    __syncthreads();

    // O-GEMM: acc[et] = W.(V^T block) + Qf.(Spre^T block); et=4 -> den
    f32x4 accs[5];
#pragma unroll 1
    for (int et = 0; et < 5; ++et) {
        f32x4 acc = {0.f, 0.f, 0.f, 0.f};
#pragma unroll
        for (int ks = 0; ks < 2; ++ks) {
            bf16x8 a = *(const bf16x8*)&sW[wv * 16 + col][ks * 32 + quad * 8];
            bf16x8 b = *(const bf16x8*)&bV[et * 16 + col][ks * 32 + quad * 8];
            acc = __builtin_amdgcn_mfma_f32_16x16x32_bf16(a, b, acc, 0, 0, 0);
        }
#pragma unroll
        for (int ks = 0; ks < 2; ++ks) {
            bf16x8 a = *(const bf16x8*)&aQ[wv * 16 + col][ks * 32 + quad * 8];
            bf16x8 b = *(const bf16x8*)&bS[et * 16 + col][ks * 32 + quad * 8];
            acc = __builtin_amdgcn_mfma_f32_16x16x32_bf16(a, b, acc, 0, 0, 0);
        }
        accs[et] = acc;
    }
    float dn[4];
#pragma unroll
    for (int j = 0; j < 4; ++j) dn[j] = __shfl(accs[4][j], lane & 48);

    float* Oc = Og + (size_t)hc * (Ll * DVv);
#pragma unroll
    for (int et = 0; et < 4; ++et) {
#pragma unroll
        for (int j = 0; j < 4; ++j) {
            const int n = wv * 16 + quad * 4 + j;
            Oc[n * DVv + et * 16 + col] = accs[et][j] / (dn[j] + EPSf);
        }
    }
}

extern "C" void kernel_launch(void* const* d_in, const int* in_sizes, int n_in,
                              void* d_out, int out_size, void* d_ws, size_t ws_size,
                              hipStream_t stream) {
    const float* Q = (const float*)d_in[0];
    const float* K = (const float*)d_in[1];
    const float* V = (const float*)d_in[2];
    __bf16* SwsT = (__bf16*)d_ws;                        // HC * 4096 bf16 = 4.2 MB
    float*  zws  = (float*)((char*)d_ws + (size_t)HCc * Dd * DVv * sizeof(__bf16));
    float* out = (float*)d_out;

    k_chunk_sums<<<HCc, 256, 0, stream>>>(K, V, SwsT, zws);
    k_output<<<HCc, 256, 0, stream>>>(Q, K, V, SwsT, zws, out);
}

// Round 5
// 88.876 us; speedup vs baseline: 2.5314x; 1.0697x over previous
//
#include <hip/hip_runtime.h>

// LinearAttention: B=1, H=16, N=2048, D=DV=64, causal=1, f32 in/out.
// Three dispatches (measured-best structure):
//  k1: per-chunk S_c^T = (Kf^T V)^T in bf16, z_c = colsum(Kf) f32.
//  kp: batched exclusive prefix scan over chunk axis (in-place, bf16).
//  k2: W = mask(Qf Kf^T), O = W V + Qf S_pre, den fused as extra column.
#define Hh   16
#define Nn   2048
#define Dd   64
#define DVv  64
#define Ll   64
#define Cc   (Nn / Ll)      // 32
#define HCc  (Hh * Cc)      // 512
#define EPSf 1e-6f
#define LDP  72             // bf16 row stride (+8 pad, keeps 16B align)

typedef __attribute__((ext_vector_type(8))) __bf16 bf16x8;
typedef __attribute__((ext_vector_type(4))) __bf16 bf16x4;
typedef __attribute__((ext_vector_type(4))) float  f32x4;

__device__ __forceinline__ float fmap(float x) {
    return x > 0.0f ? (x + 1.0f) : __expf(x);   // elu(x)+1
}
__device__ __forceinline__ __bf16 tobf(float x) { return (__bf16)x; }

// ---------------- k1: S_c^T (bf16) + z_c (f32) ----------------
__global__ __launch_bounds__(256) void k_chunk_sums(
    const float* __restrict__ Kg, const float* __restrict__ Vg,
    __bf16* __restrict__ SwsT, float* __restrict__ zws)
{
    __shared__ __align__(16) __bf16 sKT[Dd][LDP];   // Kf^T: [d][m]
    __shared__ __align__(16) __bf16 sVT[80][LDP];   // V^T: [e][m]; row 64 = ones
    const int t  = threadIdx.x;
    const int hc = blockIdx.x;
    const float4* K4 = (const float4*)(Kg + (size_t)hc * (Ll * Dd));
    const float4* V4 = (const float4*)(Vg + (size_t)hc * (Ll * DVv));
    for (int i = t; i < (Ll * Dd) / 4; i += 256) {   // 4 iters
        float4 k4 = K4[i];
        float4 v4 = V4[i];
        const int m  = i >> 4;
        const int c0 = (i & 15) * 4;
        sKT[c0 + 0][m] = tobf(fmap(k4.x));
        sKT[c0 + 1][m] = tobf(fmap(k4.y));
        sKT[c0 + 2][m] = tobf(fmap(k4.z));
        sKT[c0 + 3][m] = tobf(fmap(k4.w));
        sVT[c0 + 0][m] = tobf(v4.x);
        sVT[c0 + 1][m] = tobf(v4.y);
        sVT[c0 + 2][m] = tobf(v4.z);
        sVT[c0 + 3][m] = tobf(v4.w);
    }
    for (int i = t; i < 16 * LDP; i += 256) {        // aux rows 64..79
        const int r = i / LDP, c = i % LDP;
        sVT[64 + r][c] = (r == 0) ? (__bf16)1.0f : (__bf16)0.0f;
    }
    __syncthreads();

    const int lane = t & 63, wv = t >> 6;
    const int col = lane & 15, quad = lane >> 4;
    __bf16* So = SwsT + (size_t)hc * (Dd * DVv);     // S^T layout: [e][d]
    for (int et = 0; et < 5; ++et) {
        f32x4 acc = {0.f, 0.f, 0.f, 0.f};
#pragma unroll
        for (int ks = 0; ks < 2; ++ks) {
            bf16x8 a = *(const bf16x8*)&sKT[wv * 16 + col][ks * 32 + quad * 8];
            bf16x8 b = *(const bf16x8*)&sVT[et * 16 + col][ks * 32 + quad * 8];
            acc = __builtin_amdgcn_mfma_f32_16x16x32_bf16(a, b, acc, 0, 0, 0);
        }
        if (et < 4) {
            const int e = et * 16 + col;
            const int d = wv * 16 + quad * 4;
            bf16x4 s4 = { tobf(acc[0]), tobf(acc[1]), tobf(acc[2]), tobf(acc[3]) };
            *(bf16x4*)&So[e * Dd + d] = s4;
        } else if (col == 0) {
#pragma unroll
            for (int j = 0; j < 4; ++j)
                zws[hc * Dd + wv * 16 + quad * 4 + j] = acc[j];
        }
    }
}

// ---------------- kp: exclusive prefix over chunk axis, batched loads ---------
// Blocks 0..31: S^T slices (8192 threads x 16B). Blocks 32..35: z scans.
__global__ __launch_bounds__(256) void k_prefix(
    __bf16* __restrict__ SwsT, float* __restrict__ zws)
{
    const int b = blockIdx.x, t = threadIdx.x;
    if (b < 32) {
        const int gid = b * 256 + t;              // [0, 8192)
        const int h   = gid >> 9;                 // 512 slices per head
        const int sl  = gid & 511;
        __bf16* base = SwsT + ((size_t)h * Cc) * (Dd * DVv) + sl * 8;
        float run[8];
#pragma unroll
        for (int j = 0; j < 8; ++j) run[j] = 0.0f;
#pragma unroll
        for (int cb = 0; cb < 4; ++cb) {          // 4 batches of 8 chunks
            bf16x8 v[8];
#pragma unroll
            for (int k = 0; k < 8; ++k)
                v[k] = *(const bf16x8*)(base + (size_t)(cb * 8 + k) * (Dd * DVv));
#pragma unroll
            for (int k = 0; k < 8; ++k) {
                bf16x8 o;
#pragma unroll
                for (int j = 0; j < 8; ++j) {
                    o[j] = tobf(run[j]);
                    run[j] += (float)v[k][j];
                }
                *(bf16x8*)(base + (size_t)(cb * 8 + k) * (Dd * DVv)) = o;
            }
        }
    } else {
        const int gid = (b - 32) * 256 + t;       // [0, 1024)
        const int h = gid >> 6, d = gid & 63;
        float* zb = zws + (h * Cc) * Dd + d;
        float run = 0.0f;
#pragma unroll
        for (int cb = 0; cb < 4; ++cb) {
            float v[8];
#pragma unroll
            for (int k = 0; k < 8; ++k) v[k] = zb[(cb * 8 + k) * Dd];
#pragma unroll
            for (int k = 0; k < 8; ++k) {
                zb[(cb * 8 + k) * Dd] = run;
                run += v[k];
            }
        }
    }
}

// ---------------- k2: W-GEMM + O-GEMM, S_pre staged from ws ----------------
__global__ __launch_bounds__(256) void k_output(
    const float* __restrict__ Qg, const float* __restrict__ Kg,
    const float* __restrict__ Vg, const __bf16* __restrict__ SwsT,
    const float* __restrict__ zws, float* __restrict__ Og)
{
    __shared__ __align__(16) __bf16 aQ[Ll][LDP];    // Qf rows (A)
    __shared__ __align__(16) __bf16 aK[Ll][LDP];    // Kf rows (B^T for W-GEMM)
    __shared__ __align__(16) __bf16 sW[Ll][LDP];    // masked W (A for O-GEMM)
    __shared__ __align__(16) __bf16 bV[80][LDP];    // V^T; row 64 = ones
    __shared__ __align__(16) __bf16 bS[80][LDP];    // Spre^T; row 64 = z_pre
    const int t  = threadIdx.x;
    const int hc = blockIdx.x;
    const int lane = t & 63, wv = t >> 6;
    const int col = lane & 15, quad = lane >> 4;

    // Stage Qf / Kf / V^T
    {
        const float4* Q4 = (const float4*)(Qg + (size_t)hc * (Ll * Dd));
        const float4* K4 = (const float4*)(Kg + (size_t)hc * (Ll * Dd));
        const float4* V4 = (const float4*)(Vg + (size_t)hc * (Ll * DVv));
        for (int i = t; i < (Ll * Dd) / 4; i += 256) {
            float4 q4 = Q4[i];
            float4 k4 = K4[i];
            float4 v4 = V4[i];
            const int m  = i >> 4;
            const int c0 = (i & 15) * 4;
            bf16x4 qv = { tobf(fmap(q4.x)), tobf(fmap(q4.y)), tobf(fmap(q4.z)), tobf(fmap(q4.w)) };
            bf16x4 kv = { tobf(fmap(k4.x)), tobf(fmap(k4.y)), tobf(fmap(k4.z)), tobf(fmap(k4.w)) };
            *(bf16x4*)&aQ[m][c0] = qv;
            *(bf16x4*)&aK[m][c0] = kv;
            bV[c0 + 0][m] = tobf(v4.x);
            bV[c0 + 1][m] = tobf(v4.y);
            bV[c0 + 2][m] = tobf(v4.z);
            bV[c0 + 3][m] = tobf(v4.w);
        }
        for (int i = t; i < 16 * LDP; i += 256) {
            const int r = i / LDP, cc = i % LDP;
            bV[64 + r][cc] = (r == 0) ? (__bf16)1.0f : (__bf16)0.0f;
        }
    }

    // Stage S_pre^T (bf16, vectorized) + z_pre row
    {
        const __bf16* Sp = SwsT + (size_t)hc * (Dd * DVv);
        for (int i = t; i < (Dd * DVv) / 8; i += 256) {   // 2 iters
            bf16x8 s = *(const bf16x8*)(Sp + i * 8);
            const int e = i >> 3, d0 = (i & 7) * 8;
            *(bf16x8*)&bS[e][d0] = s;
        }
        if (t < Dd) bS[64][t] = tobf(zws[hc * Dd + t]);
        for (int i = t; i < 16 * LDP; i += 256) {
            const int r = i / LDP, cc = i % LDP;
            if (!(r == 0 && cc < Dd)) bS[64 + r][cc] = (__bf16)0.0f;
        }
    }
    __syncthreads();

    // W-GEMM: W = mask(Qf Kf^T)
#pragma unroll 1
    for (int mt = 0; mt < 4; ++mt) {
        f32x4 wacc = {0.f, 0.f, 0.f, 0.f};
#pragma unroll
        for (int ks = 0; ks < 2; ++ks) {
            bf16x8 a = *(const bf16x8*)&aQ[wv * 16 + col][ks * 32 + quad * 8];
            bf16x8 b = *(const bf16x8*)&aK[mt * 16 + col][ks * 32 + quad * 8];
            wacc = __builtin_amdgcn_mfma_f32_16x16x32_bf16(a, b, wacc, 0, 0, 0);
        }
#pragma unroll
        for (int j = 0; j < 4; ++j) {
            const int n = wv * 16 + quad * 4 + j;
            const int m = mt * 16 + col;
            sW[n][m] = tobf(m <= n ? wacc[j] : 0.0f);
        }
    }
    __syncthreads();

    // O-GEMM: acc[et] = W.(V^T block) + Qf.(Spre^T block); et=4 -> den
    f32x4 accs[5];
#pragma unroll 1
    for (int et = 0; et < 5; ++et) {
        f32x4 acc = {0.f, 0.f, 0.f, 0.f};
#pragma unroll
        for (int ks = 0; ks < 2; ++ks) {
            bf16x8 a = *(const bf16x8*)&sW[wv * 16 + col][ks * 32 + quad * 8];
            bf16x8 b = *(const bf16x8*)&bV[et * 16 + col][ks * 32 + quad * 8];
            acc = __builtin_amdgcn_mfma_f32_16x16x32_bf16(a, b, acc, 0, 0, 0);
        }
#pragma unroll
        for (int ks = 0; ks < 2; ++ks) {
            bf16x8 a = *(const bf16x8*)&aQ[wv * 16 + col][ks * 32 + quad * 8];
            bf16x8 b = *(const bf16x8*)&bS[et * 16 + col][ks * 32 + quad * 8];
            acc = __builtin_amdgcn_mfma_f32_16x16x32_bf16(a, b, acc, 0, 0, 0);
        }
        accs[et] = acc;
    }
    float dn[4];
#pragma unroll
    for (int j = 0; j < 4; ++j) dn[j] = __shfl(accs[4][j], lane & 48);

    float* Oc = Og + (size_t)hc * (Ll * DVv);
#pragma unroll
    for (int et = 0; et < 4; ++et) {
#pragma unroll
        for (int j = 0; j < 4; ++j) {
            const int n = wv * 16 + quad * 4 + j;
            Oc[n * DVv + et * 16 + col] = accs[et][j] / (dn[j] + EPSf);
        }
    }
}

extern "C" void kernel_launch(void* const* d_in, const int* in_sizes, int n_in,
                              void* d_out, int out_size, void* d_ws, size_t ws_size,
                              hipStream_t stream) {
    const float* Q = (const float*)d_in[0];
    const float* K = (const float*)d_in[1];
    const float* V = (const float*)d_in[2];
    __bf16* SwsT = (__bf16*)d_ws;                        // HC * 4096 bf16 = 4.2 MB
    float*  zws  = (float*)((char*)d_ws + (size_t)HCc * Dd * DVv * sizeof(__bf16));
    float* out = (float*)d_out;

    k_chunk_sums<<<HCc, 256, 0, stream>>>(K, V, SwsT, zws);
    k_prefix<<<36, 256, 0, stream>>>(SwsT, zws);
    k_output<<<HCc, 256, 0, stream>>>(Q, K, V, SwsT, zws, out);
}